// Round 5
// baseline (297.024 us; speedup 1.0000x reference)
//
#include <hip/hip_runtime.h>
#include <hip/hip_bf16.h>
#include <math.h>

#define N_NODES 50000
#define N_EDGES 800000
#define NEG_SLOPE 0.2f
#define SCAN_NBLK ((N_NODES + 1023) / 1024)   // 49

__device__ inline float lrelu(float x) { return x > 0.f ? x : NEG_SLOPE * x; }

// f32 -> bf16 (RNE)
__device__ inline unsigned bf16rne(float f) {
    unsigned u = __float_as_uint(f);
    return (u + 0x7fffu + ((u >> 16) & 1u)) >> 16;
}

// ---------------- CSR build ----------------
__global__ void count_kernel(const int* __restrict__ ei, int* __restrict__ counts) {
    int e = blockIdx.x * blockDim.x + threadIdx.x;
    if (e < N_EDGES) {
        int dst = ei[N_EDGES + e];
        atomicAdd(&counts[dst], 1);
    }
}

__global__ __launch_bounds__(256) void blocksum_kernel(const int* __restrict__ counts,
                                                       int* __restrict__ partials) {
    int base = blockIdx.x * 1024 + threadIdx.x * 4;
    int s = 0;
    if (base + 3 < N_NODES) {
        int4 v = *(const int4*)(counts + base);
        s = v.x + v.y + v.z + v.w;
    } else {
        #pragma unroll
        for (int i = 0; i < 4; ++i) if (base + i < N_NODES) s += counts[base + i];
    }
    #pragma unroll
    for (int off = 32; off; off >>= 1) s += __shfl_down(s, off);
    __shared__ int wsum[4];
    int lane = threadIdx.x & 63, w = threadIdx.x >> 6;
    if (lane == 0) wsum[w] = s;
    __syncthreads();
    if (threadIdx.x == 0) partials[blockIdx.x] = wsum[0] + wsum[1] + wsum[2] + wsum[3];
}

__global__ void scanpartials_kernel(int* __restrict__ partials, int* __restrict__ ptr) {
    int t = threadIdx.x;
    int v = (t < SCAN_NBLK) ? partials[t] : 0;
    #pragma unroll
    for (int off = 1; off < 64; off <<= 1) {
        int u = __shfl_up(v, off);
        if (t >= off) v += u;
    }
    if (t < SCAN_NBLK) partials[t] = v;
    if (t == 0) ptr[N_NODES] = N_EDGES;
}

__global__ __launch_bounds__(256) void downsweep_kernel(const int* __restrict__ counts,
                                                        const int* __restrict__ partials,
                                                        int* __restrict__ ptr,
                                                        int* __restrict__ cursor) {
    int b = blockIdx.x;
    int t = threadIdx.x;
    int idx = b * 1024 + t * 4;
    int v[4] = {0, 0, 0, 0};
    if (idx + 3 < N_NODES) {
        int4 q = *(const int4*)(counts + idx);
        v[0] = q.x; v[1] = q.y; v[2] = q.z; v[3] = q.w;
    } else {
        #pragma unroll
        for (int i = 0; i < 4; ++i) if (idx + i < N_NODES) v[i] = counts[idx + i];
    }
    int s = v[0] + v[1] + v[2] + v[3];
    int lane = t & 63, w = t >> 6;
    int inc = s;
    #pragma unroll
    for (int off = 1; off < 64; off <<= 1) {
        int u = __shfl_up(inc, off);
        if (lane >= off) inc += u;
    }
    __shared__ int wsum[4];
    if (lane == 63) wsum[w] = inc;
    __syncthreads();
    int wpre = 0;
    #pragma unroll
    for (int i = 0; i < 4; ++i) if (i < w) wpre += wsum[i];
    int excl = wpre + inc - s;
    int run = ((b == 0) ? 0 : partials[b - 1]) + excl;
    #pragma unroll
    for (int i = 0; i < 4; ++i) {
        if (idx + i < N_NODES) {
            ptr[idx + i] = run;
            cursor[idx + i] = run;
            run += v[i];
        }
    }
}

__global__ void scatter_kernel(const int* __restrict__ ei, int* __restrict__ cursor,
                               int* __restrict__ csr) {
    int e = blockIdx.x * blockDim.x + threadIdx.x;
    if (e < N_EDGES) {
        int src = ei[e];
        int dst = ei[N_EDGES + e];
        int pos = atomicAdd(&cursor[dst], 1);
        csr[pos] = src;
    }
}

// ---- GEMM: H[n][c] = sum_k X[n][k] * W[k][c]  (K=128, C=128), reg-blocked ----
#define GB_ROWS 64
__global__ __launch_bounds__(256) void gemm_kernel(const float* __restrict__ X,
                                                   const float* __restrict__ W,
                                                   float* __restrict__ Hout,
                                                   unsigned short* __restrict__ Hb,
                                                   int nrows) {
    __shared__ float xt[GB_ROWS][132];
    const int tid = threadIdx.x;
    const int r0 = blockIdx.x * GB_ROWS;
    #pragma unroll
    for (int i = 0; i < 8; ++i) {
        int idx = tid + 256 * i;
        int r = idx >> 5, c4 = (idx & 31) * 4;
        int gr = r0 + r;
        float4 v = make_float4(0.f, 0.f, 0.f, 0.f);
        if (gr < nrows) v = *(const float4*)(X + (size_t)gr * 128 + c4);
        *(float4*)(&xt[r][c4]) = v;
    }
    __syncthreads();
    const int c0 = (tid & 31) * 4;
    const int rbase = (tid >> 5) * 8;
    float acc[8][4];
    #pragma unroll
    for (int i = 0; i < 8; ++i)
        #pragma unroll
        for (int j = 0; j < 4; ++j) acc[i][j] = 0.f;
    #pragma unroll 4
    for (int k = 0; k < 128; ++k) {
        float4 w4 = *(const float4*)(W + k * 128 + c0);
        float xv[8];
        #pragma unroll
        for (int i = 0; i < 8; ++i) xv[i] = xt[rbase + i][k];
        #pragma unroll
        for (int i = 0; i < 8; ++i) {
            acc[i][0] = fmaf(xv[i], w4.x, acc[i][0]);
            acc[i][1] = fmaf(xv[i], w4.y, acc[i][1]);
            acc[i][2] = fmaf(xv[i], w4.z, acc[i][2]);
            acc[i][3] = fmaf(xv[i], w4.w, acc[i][3]);
        }
    }
    #pragma unroll
    for (int i = 0; i < 8; ++i) {
        int gr = r0 + rbase + i;
        if (gr < nrows) {
            *(float4*)(Hout + (size_t)gr * 128 + c0) =
                make_float4(acc[i][0], acc[i][1], acc[i][2], acc[i][3]);
            uint2 p;
            p.x = bf16rne(acc[i][0]) | (bf16rne(acc[i][1]) << 16);
            p.y = bf16rne(acc[i][2]) | (bf16rne(acc[i][3]) << 16);
            *(uint2*)(Hb + (size_t)gr * 128 + c0) = p;
        }
    }
}

// ---------------- per-node attention logits ----------------
template <int H>
__global__ __launch_bounds__(256) void alpha_kernel(const float* __restrict__ Hm,
                                                    const float* __restrict__ a_src,
                                                    const float* __restrict__ a_dst,
                                                    float* __restrict__ als,
                                                    float* __restrict__ ald) {
    int wid = ((blockIdx.x * blockDim.x + threadIdx.x) >> 6);
    int lane = threadIdx.x & 63;
    if (wid >= N_NODES) return;
    float v0 = Hm[(size_t)wid * 128 + lane];
    float v1 = Hm[(size_t)wid * 128 + 64 + lane];
    if (H == 2) {
        float s0 = v0 * a_src[lane];
        float s1 = v1 * a_src[64 + lane];
        float d0 = v0 * a_dst[lane];
        float d1 = v1 * a_dst[64 + lane];
        #pragma unroll
        for (int off = 32; off; off >>= 1) {
            s0 += __shfl_down(s0, off);
            s1 += __shfl_down(s1, off);
            d0 += __shfl_down(d0, off);
            d1 += __shfl_down(d1, off);
        }
        if (lane == 0) {
            als[wid * 2] = s0; als[wid * 2 + 1] = s1;
            ald[wid * 2] = d0; ald[wid * 2 + 1] = d1;
        }
    } else {
        float s = v0 * a_src[lane] + v1 * a_src[64 + lane];
        float d = v0 * a_dst[lane] + v1 * a_dst[64 + lane];
        #pragma unroll
        for (int off = 32; off; off >>= 1) {
            s += __shfl_down(s, off);
            d += __shfl_down(d, off);
        }
        if (lane == 0) { als[wid] = s; ald[wid] = d; }
    }
}

// ---- phase A: per-edge normalized attention weights (lanes stride edges) ----
template <int H>
__global__ __launch_bounds__(256) void edgealpha_kernel(const float* __restrict__ als,
                                                        const float* __restrict__ aldv,
                                                        const int* __restrict__ ptr,
                                                        const int* __restrict__ csr,
                                                        float* __restrict__ alpha,
                                                        float* __restrict__ salpha) {
    int d = blockIdx.x * 4 + (threadIdx.x >> 6);
    int lane = threadIdx.x & 63;
    if (d >= N_NODES) return;
    int beg = ptr[d], end = ptr[d + 1];
    float ald0 = aldv[d * H];
    float ald1 = (H == 2) ? aldv[d * H + 1] : 0.f;
    float es0 = lrelu(als[d * H] + ald0);
    float es1 = (H == 2) ? lrelu(als[d * H + 1] + ald1) : 0.f;
    int k0 = beg + lane;
    bool v0 = k0 < end;
    int s0 = v0 ? csr[k0] : 0;
    float e0 = -INFINITY, e1 = -INFINITY;
    if (v0) {
        e0 = lrelu(als[s0 * H] + ald0);
        if (H == 2) e1 = lrelu(als[s0 * H + 1] + ald1);
    }
    float m0 = fmaxf(es0, e0);
    float m1 = (H == 2) ? fmaxf(es1, e1) : 0.f;
    for (int k = k0 + 64; k < end; k += 64) {   // deg>64: rare, recompute path
        int s = csr[k];
        m0 = fmaxf(m0, lrelu(als[s * H] + ald0));
        if (H == 2) m1 = fmaxf(m1, lrelu(als[s * H + 1] + ald1));
    }
    #pragma unroll
    for (int off = 32; off; off >>= 1) {
        m0 = fmaxf(m0, __shfl_xor(m0, off));
        if (H == 2) m1 = fmaxf(m1, __shfl_xor(m1, off));
    }
    float p0 = v0 ? __expf(e0 - m0) : 0.f;
    float p1 = (H == 2 && v0) ? __expf(e1 - m1) : 0.f;
    float t0 = p0, t1 = p1;
    for (int k = k0 + 64; k < end; k += 64) {
        int s = csr[k];
        t0 += __expf(lrelu(als[s * H] + ald0) - m0);
        if (H == 2) t1 += __expf(lrelu(als[s * H + 1] + ald1) - m1);
    }
    #pragma unroll
    for (int off = 32; off; off >>= 1) {
        t0 += __shfl_xor(t0, off);
        if (H == 2) t1 += __shfl_xor(t1, off);
    }
    float ps0 = __expf(es0 - m0);
    float ps1 = (H == 2) ? __expf(es1 - m1) : 0.f;
    float inv0 = 1.f / (t0 + ps0 + 1e-16f);
    float inv1 = (H == 2) ? 1.f / (t1 + ps1 + 1e-16f) : 0.f;
    if (v0) {
        if (H == 2) *(float2*)(alpha + (size_t)k0 * 2) = make_float2(p0 * inv0, p1 * inv1);
        else alpha[k0] = p0 * inv0;
    }
    for (int k = k0 + 64; k < end; k += 64) {
        int s = csr[k];
        float q0 = __expf(lrelu(als[s * H] + ald0) - m0) * inv0;
        if (H == 2) {
            float q1 = __expf(lrelu(als[s * H + 1] + ald1) - m1) * inv1;
            *(float2*)(alpha + (size_t)k * 2) = make_float2(q0, q1);
        } else alpha[k] = q0;
    }
    if (lane == 0) {
        salpha[d * H] = ps0 * inv0;
        if (H == 2) salpha[d * H + 1] = ps1 * inv1;
    }
}

// ---- phase B: weighted gather (one wave per dst; bf16 features) ----
template <int H, int DO_ELU>
__global__ __launch_bounds__(256) void gather_kernel(const unsigned short* __restrict__ Hb,
                                                     const float* __restrict__ alpha,
                                                     const float* __restrict__ salpha,
                                                     const int* __restrict__ ptr,
                                                     const int* __restrict__ csr,
                                                     const float* __restrict__ bias,
                                                     float* __restrict__ out) {
    int d = blockIdx.x * 4 + (threadIdx.x >> 6);
    int lane = threadIdx.x & 63;
    if (d >= N_NODES) return;
    const int head = (H == 2) ? (lane >> 5) : 0;
    float accx, accy;
    {
        float sa = salpha[d * H + head];
        unsigned u = ((const unsigned*)(Hb + (size_t)d * 128))[lane];
        accx = sa * __uint_as_float(u << 16);
        accy = sa * __uint_as_float(u & 0xffff0000u);
    }
    int beg = ptr[d], end = ptr[d + 1];
    int k = beg;
#define GSTEP(KK, SS) do {                                                    \
        float _a = alpha[(size_t)(KK) * H + head];                            \
        unsigned _u = ((const unsigned*)(Hb + (size_t)(SS) * 128))[lane];     \
        accx = fmaf(_a, __uint_as_float(_u << 16), accx);                     \
        accy = fmaf(_a, __uint_as_float(_u & 0xffff0000u), accy);             \
    } while (0)
    for (; k + 3 < end; k += 4) {
        int s0 = csr[k], s1 = csr[k + 1], s2 = csr[k + 2], s3 = csr[k + 3];
        GSTEP(k, s0);
        GSTEP(k + 1, s1);
        GSTEP(k + 2, s2);
        GSTEP(k + 3, s3);
    }
    for (; k < end; ++k) {
        int s = csr[k];
        GSTEP(k, s);
    }
#undef GSTEP
    float o0 = accx + bias[2 * lane];
    float o1 = accy + bias[2 * lane + 1];
    if (DO_ELU) {
        o0 = o0 > 0.f ? o0 : expm1f(o0);
        o1 = o1 > 0.f ? o1 : expm1f(o1);
    }
    ((float2*)(out + (size_t)d * 128))[lane] = make_float2(o0, o1);
}

// ---------------- launch ----------------
extern "C" void kernel_launch(void* const* d_in, const int* in_sizes, int n_in,
                              void* d_out, int out_size, void* d_ws, size_t ws_size,
                              hipStream_t stream) {
    const float* x      = (const float*)d_in[0];
    const int*   ei     = (const int*)d_in[1];
    const float* W1     = (const float*)d_in[2];
    const float* a_src1 = (const float*)d_in[3];
    const float* a_dst1 = (const float*)d_in[4];
    const float* b1     = (const float*)d_in[5];
    const float* W2     = (const float*)d_in[6];
    const float* a_src2 = (const float*)d_in[7];
    const float* a_dst2 = (const float*)d_in[8];
    const float* b2     = (const float*)d_in[9];
    float* out = (float*)d_out;

    char* ws = (char*)d_ws;
    size_t off = 0;
    auto alloc = [&](size_t bytes) { void* p = ws + off; off += (bytes + 255) & ~(size_t)255; return p; };
    int*   ptr      = (int*)alloc((N_NODES + 1) * sizeof(int));
    int*   cursor   = (int*)alloc(N_NODES * sizeof(int));
    int*   counts   = (int*)alloc(N_NODES * sizeof(int));
    int*   partials = (int*)alloc(SCAN_NBLK * sizeof(int));
    int*   csr      = (int*)alloc(N_EDGES * sizeof(int));
    float* h        = (float*)alloc((size_t)N_NODES * 128 * sizeof(float));
    float* x2       = (float*)alloc((size_t)N_NODES * 128 * sizeof(float));
    unsigned short* hb = (unsigned short*)alloc((size_t)N_NODES * 128 * sizeof(unsigned short));
    float* als      = (float*)alloc(N_NODES * 2 * sizeof(float));
    float* ald      = (float*)alloc(N_NODES * 2 * sizeof(float));
    float* alpha    = (float*)alloc((size_t)N_EDGES * 2 * sizeof(float));
    float* salpha   = (float*)alloc(N_NODES * 2 * sizeof(float));

    // ---- CSR build (same graph both layers) ----
    hipMemsetAsync(counts, 0, N_NODES * sizeof(int), stream);
    int eblocks = (N_EDGES + 255) / 256;
    count_kernel<<<eblocks, 256, 0, stream>>>(ei, counts);
    blocksum_kernel<<<SCAN_NBLK, 256, 0, stream>>>(counts, partials);
    scanpartials_kernel<<<1, 64, 0, stream>>>(partials, ptr);
    downsweep_kernel<<<SCAN_NBLK, 256, 0, stream>>>(counts, partials, ptr, cursor);
    scatter_kernel<<<eblocks, 256, 0, stream>>>(ei, cursor, csr);

    int gblocks = (N_NODES + GB_ROWS - 1) / GB_ROWS;
    int wblocks = (N_NODES + 3) / 4;

    // ---- layer 1 ----
    gemm_kernel<<<gblocks, 256, 0, stream>>>(x, W1, h, hb, N_NODES);
    alpha_kernel<2><<<wblocks, 256, 0, stream>>>(h, a_src1, a_dst1, als, ald);
    edgealpha_kernel<2><<<wblocks, 256, 0, stream>>>(als, ald, ptr, csr, alpha, salpha);
    gather_kernel<2, 1><<<wblocks, 256, 0, stream>>>(hb, alpha, salpha, ptr, csr, b1, x2);

    // ---- layer 2 ----
    gemm_kernel<<<gblocks, 256, 0, stream>>>(x2, W2, h, hb, N_NODES);
    alpha_kernel<1><<<wblocks, 256, 0, stream>>>(h, a_src2, a_dst2, als, ald);
    edgealpha_kernel<1><<<wblocks, 256, 0, stream>>>(als, ald, ptr, csr, alpha, salpha);
    gather_kernel<1, 0><<<wblocks, 256, 0, stream>>>(hb, alpha, salpha, ptr, csr, b2, out);
}

// Round 6
// 226.266 us; speedup vs baseline: 1.3127x; 1.3127x over previous
//
#include <hip/hip_runtime.h>
#include <hip/hip_bf16.h>
#include <math.h>

#define N_NODES 50000
#define N_EDGES 800000
#define NEG_SLOPE 0.2f
#define NBUCK ((N_NODES + 255) / 256)   // 196 buckets of 256 dsts
#define CCHUNK 4096                     // edges staged per block in bucketscatter
#define DCAP 8192                       // LDS pair capacity in csrfinalize (mean 4082, +64 sigma)

__device__ inline unsigned bf16rne(float f) {
    unsigned u = __float_as_uint(f);
    return (u + 0x7fffu + ((u >> 16) & 1u)) >> 16;
}

// ---------------- CSR build: LDS-staged bucket sort ----------------
// Phase A: global bucket histogram (LDS-staged)
__global__ __launch_bounds__(256) void bucketcount_kernel(const int* __restrict__ ei,
                                                          int* __restrict__ gbcnt) {
    __shared__ int lc[NBUCK];
    for (int i = threadIdx.x; i < NBUCK; i += 256) lc[i] = 0;
    __syncthreads();
    int stride = gridDim.x * 256;
    for (int e = blockIdx.x * 256 + threadIdx.x; e < N_EDGES; e += stride)
        atomicAdd(&lc[ei[N_EDGES + e] >> 8], 1);
    __syncthreads();
    for (int i = threadIdx.x; i < NBUCK; i += 256)
        if (lc[i]) atomicAdd(&gbcnt[i], lc[i]);
}

// Phase B: scan bucket counts -> bases + cursors
__global__ __launch_bounds__(256) void bucketscan_kernel(const int* __restrict__ gbcnt,
                                                         int* __restrict__ bbase,
                                                         int* __restrict__ bcur) {
    __shared__ int ss[256];
    int t = threadIdx.x;
    int v = (t < NBUCK) ? gbcnt[t] : 0;
    ss[t] = v;
    __syncthreads();
    for (int d = 1; d < 256; d <<= 1) {
        int u = (t >= d) ? ss[t - d] : 0;
        __syncthreads();
        ss[t] += u;
        __syncthreads();
    }
    int excl = ss[t] - v;
    if (t < NBUCK) { bbase[t] = excl; bcur[t] = excl; }
    if (t == 0) bbase[NBUCK] = N_EDGES;
}

// Phase C: stage CCHUNK edges in LDS ordered by bucket, bulk-reserve, write runs
__global__ __launch_bounds__(256) void bucketscatter_kernel(const int* __restrict__ ei,
                                                            int* __restrict__ bcur,
                                                            int2* __restrict__ bpairs) {
    __shared__ int cnt[NBUCK], startl[NBUCK], baseg[NBUCK], cur2[NBUCK];
    __shared__ int ss[256];
    __shared__ int2 stage[CCHUNK];
    int t = threadIdx.x;
    int e0 = blockIdx.x * CCHUNK;
    int nume = min(CCHUNK, N_EDGES - e0);
    for (int i = t; i < NBUCK; i += 256) { cnt[i] = 0; cur2[i] = 0; }
    __syncthreads();
    int src[CCHUNK / 256], dst[CCHUNK / 256];
    #pragma unroll
    for (int j = 0; j < CCHUNK / 256; ++j) {
        int idx = t + j * 256;
        if (idx < nume) {
            src[j] = ei[e0 + idx];
            dst[j] = ei[N_EDGES + e0 + idx];
            atomicAdd(&cnt[dst[j] >> 8], 1);
        } else dst[j] = -1;
    }
    __syncthreads();
    {   // exclusive scan of cnt -> startl
        int v = (t < NBUCK) ? cnt[t] : 0;
        ss[t] = v;
        __syncthreads();
        for (int d = 1; d < 256; d <<= 1) {
            int u = (t >= d) ? ss[t - d] : 0;
            __syncthreads();
            ss[t] += u;
            __syncthreads();
        }
        if (t < NBUCK) startl[t] = ss[t] - v;
    }
    __syncthreads();
    if (t < NBUCK && cnt[t] > 0) baseg[t] = atomicAdd(&bcur[t], cnt[t]);
    __syncthreads();
    #pragma unroll
    for (int j = 0; j < CCHUNK / 256; ++j) {
        if (dst[j] >= 0) {
            int b = dst[j] >> 8;
            int slot = startl[b] + atomicAdd(&cur2[b], 1);
            stage[slot] = make_int2(src[j], dst[j]);
        }
    }
    __syncthreads();
    for (int i = t; i < nume; i += 256) {
        int2 p = stage[i];
        int b = p.y >> 8;
        bpairs[baseg[b] + (i - startl[b])] = p;
    }
}

// Phase D: one block per bucket; per-dst count/scan in LDS; write ptr + csr
__global__ __launch_bounds__(256) void csrfinalize_kernel(const int2* __restrict__ bpairs,
                                                          const int* __restrict__ bbase,
                                                          int* __restrict__ ptr,
                                                          int* __restrict__ csr) {
    __shared__ int cnt[256], excl[256], cur[256];
    __shared__ int ss[256];
    __shared__ int2 P[DCAP];
    int b = blockIdx.x, t = threadIdx.x;
    int bb = bbase[b], be = bbase[b + 1];
    int n = be - bb;
    int d0 = b << 8;
    int dmax = min(256, N_NODES - d0);
    bool fits = (n <= DCAP);
    cnt[t] = 0; cur[t] = 0;
    __syncthreads();
    for (int i = t; i < n; i += 256) {
        int2 p = bpairs[bb + i];
        if (fits) P[i] = p;
        atomicAdd(&cnt[p.y & 255], 1);
    }
    __syncthreads();
    {   // exclusive scan of cnt
        int v = cnt[t];
        ss[t] = v;
        __syncthreads();
        for (int d = 1; d < 256; d <<= 1) {
            int u = (t >= d) ? ss[t - d] : 0;
            __syncthreads();
            ss[t] += u;
            __syncthreads();
        }
        excl[t] = ss[t] - v;
    }
    __syncthreads();
    if (t < dmax) ptr[d0 + t] = bb + excl[t];
    if (b == NBUCK - 1 && t == 0) ptr[N_NODES] = N_EDGES;
    for (int i = t; i < n; i += 256) {
        int2 p = fits ? P[i] : bpairs[bb + i];
        int ld = p.y & 255;
        int pos = bb + excl[ld] + atomicAdd(&cur[ld], 1);
        csr[pos] = p.x;
    }
}

// ---- GEMM: H[n][c] = sum_k X[n][k] * W[k][c]  (K=128, C=128), reg-blocked ----
#define GB_ROWS 64
__global__ __launch_bounds__(256) void gemm_kernel(const float* __restrict__ X,
                                                   const float* __restrict__ W,
                                                   float* __restrict__ Hout,
                                                   unsigned short* __restrict__ Hb,
                                                   int nrows) {
    __shared__ float xt[GB_ROWS][132];
    const int tid = threadIdx.x;
    const int r0 = blockIdx.x * GB_ROWS;
    #pragma unroll
    for (int i = 0; i < 8; ++i) {
        int idx = tid + 256 * i;
        int r = idx >> 5, c4 = (idx & 31) * 4;
        int gr = r0 + r;
        float4 v = make_float4(0.f, 0.f, 0.f, 0.f);
        if (gr < nrows) v = *(const float4*)(X + (size_t)gr * 128 + c4);
        *(float4*)(&xt[r][c4]) = v;
    }
    __syncthreads();
    const int c0 = (tid & 31) * 4;
    const int rbase = (tid >> 5) * 8;
    float acc[8][4];
    #pragma unroll
    for (int i = 0; i < 8; ++i)
        #pragma unroll
        for (int j = 0; j < 4; ++j) acc[i][j] = 0.f;
    #pragma unroll 4
    for (int k = 0; k < 128; ++k) {
        float4 w4 = *(const float4*)(W + k * 128 + c0);
        float xv[8];
        #pragma unroll
        for (int i = 0; i < 8; ++i) xv[i] = xt[rbase + i][k];
        #pragma unroll
        for (int i = 0; i < 8; ++i) {
            acc[i][0] = fmaf(xv[i], w4.x, acc[i][0]);
            acc[i][1] = fmaf(xv[i], w4.y, acc[i][1]);
            acc[i][2] = fmaf(xv[i], w4.z, acc[i][2]);
            acc[i][3] = fmaf(xv[i], w4.w, acc[i][3]);
        }
    }
    #pragma unroll
    for (int i = 0; i < 8; ++i) {
        int gr = r0 + rbase + i;
        if (gr < nrows) {
            *(float4*)(Hout + (size_t)gr * 128 + c0) =
                make_float4(acc[i][0], acc[i][1], acc[i][2], acc[i][3]);
            uint2 p;
            p.x = bf16rne(acc[i][0]) | (bf16rne(acc[i][1]) << 16);
            p.y = bf16rne(acc[i][2]) | (bf16rne(acc[i][3]) << 16);
            *(uint2*)(Hb + (size_t)gr * 128 + c0) = p;
        }
    }
}

// ---------------- per-node attention logits ----------------
template <int H>
__global__ __launch_bounds__(256) void alpha_kernel(const float* __restrict__ Hm,
                                                    const float* __restrict__ a_src,
                                                    const float* __restrict__ a_dst,
                                                    float* __restrict__ als,
                                                    float* __restrict__ ald) {
    int wid = ((blockIdx.x * blockDim.x + threadIdx.x) >> 6);
    int lane = threadIdx.x & 63;
    if (wid >= N_NODES) return;
    float v0 = Hm[(size_t)wid * 128 + lane];
    float v1 = Hm[(size_t)wid * 128 + 64 + lane];
    if (H == 2) {
        float s0 = v0 * a_src[lane];
        float s1 = v1 * a_src[64 + lane];
        float d0 = v0 * a_dst[lane];
        float d1 = v1 * a_dst[64 + lane];
        #pragma unroll
        for (int off = 32; off; off >>= 1) {
            s0 += __shfl_down(s0, off);
            s1 += __shfl_down(s1, off);
            d0 += __shfl_down(d0, off);
            d1 += __shfl_down(d1, off);
        }
        if (lane == 0) {
            als[wid * 2] = s0; als[wid * 2 + 1] = s1;
            ald[wid * 2] = d0; ald[wid * 2 + 1] = d1;
        }
    } else {
        float s = v0 * a_src[lane] + v1 * a_src[64 + lane];
        float d = v0 * a_dst[lane] + v1 * a_dst[64 + lane];
        #pragma unroll
        for (int off = 32; off; off >>= 1) {
            s += __shfl_down(s, off);
            d += __shfl_down(d, off);
        }
        if (lane == 0) { als[wid] = s; ald[wid] = d; }
    }
}

// ---- fused edge-softmax + aggregation (one wave per dst; bf16 gathers) ----
template <int H, int DO_ELU>
__global__ __launch_bounds__(256) void aggregate_kernel(const unsigned short* __restrict__ Hb,
                                                        const float* __restrict__ als,
                                                        const float* __restrict__ aldv,
                                                        const int* __restrict__ ptr,
                                                        const int* __restrict__ csr,
                                                        const float* __restrict__ bias,
                                                        float* __restrict__ out) {
    int wid = blockIdx.x * (blockDim.x >> 6) + (threadIdx.x >> 6);
    int lane = threadIdx.x & 63;
    if (wid >= N_NODES) return;
    const int d = wid;
    const int head = (H == 2) ? (lane >> 5) : 0;
    const float ald = aldv[d * H + head];

    float m0, m1, m2, m3, l0, l1, l2, l3;
    float a0x, a0y, a1x, a1y, a2x, a2y, a3x, a3y;
    { // state 0 init = self-loop
        float e = als[d * H + head] + ald;
        e = e > 0.f ? e : NEG_SLOPE * e;
        m0 = e; l0 = 1.f;
        unsigned u = ((const unsigned*)(Hb + (size_t)d * 128))[lane];
        a0x = __uint_as_float(u << 16);
        a0y = __uint_as_float(u & 0xffff0000u);
    }
    m1 = m2 = m3 = -INFINITY;
    l1 = l2 = l3 = 0.f;
    a1x = a1y = a2x = a2y = a3x = a3y = 0.f;

#define UPDATE(S, SRC) do {                                                   \
        int _s = (SRC);                                                       \
        float _e = als[_s * H + head] + ald;                                  \
        _e = _e > 0.f ? _e : NEG_SLOPE * _e;                                  \
        unsigned _u = ((const unsigned*)(Hb + (size_t)_s * 128))[lane];       \
        float _hx = __uint_as_float(_u << 16);                                \
        float _hy = __uint_as_float(_u & 0xffff0000u);                        \
        float _mn = fmaxf(m##S, _e);                                          \
        float _sc = __expf(m##S - _mn);                                       \
        float _p  = __expf(_e - _mn);                                         \
        l##S  = fmaf(l##S, _sc, _p);                                          \
        a##S##x = fmaf(a##S##x, _sc, _p * _hx);                               \
        a##S##y = fmaf(a##S##y, _sc, _p * _hy);                               \
        m##S = _mn;                                                           \
    } while (0)

    int beg = ptr[d], end = ptr[d + 1];
    int k = beg;
    for (; k + 3 < end; k += 4) {
        int s0 = csr[k], s1 = csr[k + 1], s2 = csr[k + 2], s3 = csr[k + 3];
        UPDATE(0, s0);
        UPDATE(1, s1);
        UPDATE(2, s2);
        UPDATE(3, s3);
    }
    if (k < end) { UPDATE(0, csr[k]); ++k; }
    if (k < end) { UPDATE(1, csr[k]); ++k; }
    if (k < end) { UPDATE(2, csr[k]); ++k; }
#undef UPDATE

    float M = fmaxf(fmaxf(m0, m1), fmaxf(m2, m3));
    float w0 = __expf(m0 - M), w1 = __expf(m1 - M);
    float w2 = __expf(m2 - M), w3 = __expf(m3 - M);
    float L  = l0 * w0 + l1 * w1 + l2 * w2 + l3 * w3;
    float ax = a0x * w0 + a1x * w1 + a2x * w2 + a3x * w3;
    float ay = a0y * w0 + a1y * w1 + a2y * w2 + a3y * w3;

    float inv = 1.f / (L + 1e-16f);
    float o0 = ax * inv + bias[2 * lane];
    float o1 = ay * inv + bias[2 * lane + 1];
    if (DO_ELU) {
        o0 = o0 > 0.f ? o0 : expm1f(o0);
        o1 = o1 > 0.f ? o1 : expm1f(o1);
    }
    ((float2*)(out + (size_t)d * 128))[lane] = make_float2(o0, o1);
}

// ---------------- launch ----------------
extern "C" void kernel_launch(void* const* d_in, const int* in_sizes, int n_in,
                              void* d_out, int out_size, void* d_ws, size_t ws_size,
                              hipStream_t stream) {
    const float* x      = (const float*)d_in[0];
    const int*   ei     = (const int*)d_in[1];
    const float* W1     = (const float*)d_in[2];
    const float* a_src1 = (const float*)d_in[3];
    const float* a_dst1 = (const float*)d_in[4];
    const float* b1     = (const float*)d_in[5];
    const float* W2     = (const float*)d_in[6];
    const float* a_src2 = (const float*)d_in[7];
    const float* a_dst2 = (const float*)d_in[8];
    const float* b2     = (const float*)d_in[9];
    float* out = (float*)d_out;

    char* ws = (char*)d_ws;
    size_t off = 0;
    auto alloc = [&](size_t bytes) { void* p = ws + off; off += (bytes + 255) & ~(size_t)255; return p; };
    int*   ptr    = (int*)alloc((N_NODES + 1) * sizeof(int));
    int*   gbcnt  = (int*)alloc(NBUCK * sizeof(int));
    int*   bbase  = (int*)alloc((NBUCK + 1) * sizeof(int));
    int*   bcur   = (int*)alloc(NBUCK * sizeof(int));
    int2*  bpairs = (int2*)alloc((size_t)N_EDGES * sizeof(int2));
    int*   csr    = (int*)alloc(N_EDGES * sizeof(int));
    float* h      = (float*)alloc((size_t)N_NODES * 128 * sizeof(float));
    float* x2     = (float*)alloc((size_t)N_NODES * 128 * sizeof(float));
    unsigned short* hb = (unsigned short*)alloc((size_t)N_NODES * 128 * sizeof(unsigned short));
    float* als    = (float*)alloc(N_NODES * 2 * sizeof(float));
    float* ald    = (float*)alloc(N_NODES * 2 * sizeof(float));

    // ---- CSR build (bucket sort; same graph both layers) ----
    hipMemsetAsync(gbcnt, 0, NBUCK * sizeof(int), stream);
    bucketcount_kernel<<<256, 256, 0, stream>>>(ei, gbcnt);
    bucketscan_kernel<<<1, 256, 0, stream>>>(gbcnt, bbase, bcur);
    bucketscatter_kernel<<<(N_EDGES + CCHUNK - 1) / CCHUNK, 256, 0, stream>>>(ei, bcur, bpairs);
    csrfinalize_kernel<<<NBUCK, 256, 0, stream>>>(bpairs, bbase, ptr, csr);

    int gblocks = (N_NODES + GB_ROWS - 1) / GB_ROWS;
    int wblocks = (N_NODES + 3) / 4;

    // ---- layer 1 ----
    gemm_kernel<<<gblocks, 256, 0, stream>>>(x, W1, h, hb, N_NODES);
    alpha_kernel<2><<<wblocks, 256, 0, stream>>>(h, a_src1, a_dst1, als, ald);
    aggregate_kernel<2, 1><<<wblocks, 256, 0, stream>>>(hb, als, ald, ptr, csr, b1, x2);

    // ---- layer 2 ----
    gemm_kernel<<<gblocks, 256, 0, stream>>>(x2, W2, h, hb, N_NODES);
    alpha_kernel<1><<<wblocks, 256, 0, stream>>>(h, a_src2, a_dst2, als, ald);
    aggregate_kernel<1, 0><<<wblocks, 256, 0, stream>>>(hb, als, ald, ptr, csr, b2, out);
}

// Round 7
// 218.582 us; speedup vs baseline: 1.3589x; 1.0352x over previous
//
#include <hip/hip_runtime.h>
#include <hip/hip_bf16.h>
#include <math.h>

#define N_NODES 50000
#define N_EDGES 800000
#define NEG_SLOPE 0.2f
#define NBUCK ((N_NODES + 255) / 256)   // 196 buckets of 256 dsts
#define CCHUNK 4096                     // edges staged per block in bucketscatter
#define DCAP 8192                       // LDS pair capacity in csrfinalize

__device__ inline float lrelu(float x) { return fmaxf(x, NEG_SLOPE * x); }

__device__ inline unsigned bf16rne(float f) {
    unsigned u = __float_as_uint(f);
    return (u + 0x7fffu + ((u >> 16) & 1u)) >> 16;
}

// ---------------- CSR build: LDS-staged bucket sort ----------------
__global__ __launch_bounds__(256) void bucketcount_kernel(const int* __restrict__ ei,
                                                          int* __restrict__ gbcnt) {
    __shared__ int lc[NBUCK];
    for (int i = threadIdx.x; i < NBUCK; i += 256) lc[i] = 0;
    __syncthreads();
    int stride = gridDim.x * 256;
    for (int e = blockIdx.x * 256 + threadIdx.x; e < N_EDGES; e += stride)
        atomicAdd(&lc[ei[N_EDGES + e] >> 8], 1);
    __syncthreads();
    for (int i = threadIdx.x; i < NBUCK; i += 256)
        if (lc[i]) atomicAdd(&gbcnt[i], lc[i]);
}

__global__ __launch_bounds__(256) void bucketscan_kernel(const int* __restrict__ gbcnt,
                                                         int* __restrict__ bbase,
                                                         int* __restrict__ bcur) {
    __shared__ int ss[256];
    int t = threadIdx.x;
    int v = (t < NBUCK) ? gbcnt[t] : 0;
    ss[t] = v;
    __syncthreads();
    for (int d = 1; d < 256; d <<= 1) {
        int u = (t >= d) ? ss[t - d] : 0;
        __syncthreads();
        ss[t] += u;
        __syncthreads();
    }
    int excl = ss[t] - v;
    if (t < NBUCK) { bbase[t] = excl; bcur[t] = excl; }
    if (t == 0) bbase[NBUCK] = N_EDGES;
}

__global__ __launch_bounds__(256) void bucketscatter_kernel(const int* __restrict__ ei,
                                                            int* __restrict__ bcur,
                                                            int2* __restrict__ bpairs) {
    __shared__ int cnt[NBUCK], startl[NBUCK], baseg[NBUCK], cur2[NBUCK];
    __shared__ int ss[256];
    __shared__ int2 stage[CCHUNK];
    int t = threadIdx.x;
    int e0 = blockIdx.x * CCHUNK;
    int nume = min(CCHUNK, N_EDGES - e0);
    for (int i = t; i < NBUCK; i += 256) { cnt[i] = 0; cur2[i] = 0; }
    __syncthreads();
    int src[CCHUNK / 256], dst[CCHUNK / 256];
    #pragma unroll
    for (int j = 0; j < CCHUNK / 256; ++j) {
        int idx = t + j * 256;
        if (idx < nume) {
            src[j] = ei[e0 + idx];
            dst[j] = ei[N_EDGES + e0 + idx];
            atomicAdd(&cnt[dst[j] >> 8], 1);
        } else dst[j] = -1;
    }
    __syncthreads();
    {
        int v = (t < NBUCK) ? cnt[t] : 0;
        ss[t] = v;
        __syncthreads();
        for (int d = 1; d < 256; d <<= 1) {
            int u = (t >= d) ? ss[t - d] : 0;
            __syncthreads();
            ss[t] += u;
            __syncthreads();
        }
        if (t < NBUCK) startl[t] = ss[t] - v;
    }
    __syncthreads();
    if (t < NBUCK && cnt[t] > 0) baseg[t] = atomicAdd(&bcur[t], cnt[t]);
    __syncthreads();
    #pragma unroll
    for (int j = 0; j < CCHUNK / 256; ++j) {
        if (dst[j] >= 0) {
            int b = dst[j] >> 8;
            int slot = startl[b] + atomicAdd(&cur2[b], 1);
            stage[slot] = make_int2(src[j], dst[j]);
        }
    }
    __syncthreads();
    for (int i = t; i < nume; i += 256) {
        int2 p = stage[i];
        int b = p.y >> 8;
        bpairs[baseg[b] + (i - startl[b])] = p;
    }
}

__global__ __launch_bounds__(256) void csrfinalize_kernel(const int2* __restrict__ bpairs,
                                                          const int* __restrict__ bbase,
                                                          int* __restrict__ ptr,
                                                          int* __restrict__ csr) {
    __shared__ int cnt[256], excl[256], cur[256];
    __shared__ int ss[256];
    __shared__ int2 P[DCAP];
    int b = blockIdx.x, t = threadIdx.x;
    int bb = bbase[b], be = bbase[b + 1];
    int n = be - bb;
    int d0 = b << 8;
    int dmax = min(256, N_NODES - d0);
    bool fits = (n <= DCAP);
    cnt[t] = 0; cur[t] = 0;
    __syncthreads();
    for (int i = t; i < n; i += 256) {
        int2 p = bpairs[bb + i];
        if (fits) P[i] = p;
        atomicAdd(&cnt[p.y & 255], 1);
    }
    __syncthreads();
    {
        int v = cnt[t];
        ss[t] = v;
        __syncthreads();
        for (int d = 1; d < 256; d <<= 1) {
            int u = (t >= d) ? ss[t - d] : 0;
            __syncthreads();
            ss[t] += u;
            __syncthreads();
        }
        excl[t] = ss[t] - v;
    }
    __syncthreads();
    if (t < dmax) ptr[d0 + t] = bb + excl[t];
    if (b == NBUCK - 1 && t == 0) ptr[N_NODES] = N_EDGES;
    for (int i = t; i < n; i += 256) {
        int2 p = fits ? P[i] : bpairs[bb + i];
        int ld = p.y & 255;
        int pos = bb + excl[ld] + atomicAdd(&cur[ld], 1);
        csr[pos] = p.x;
    }
}

// ---- GEMM: H[n][c] = sum_k X[n][k] * W[k][c]  (K=128, C=128), reg-blocked ----
#define GB_ROWS 64
__global__ __launch_bounds__(256) void gemm_kernel(const float* __restrict__ X,
                                                   const float* __restrict__ W,
                                                   float* __restrict__ Hout,
                                                   unsigned short* __restrict__ Hb,
                                                   int nrows) {
    __shared__ float xt[GB_ROWS][132];
    const int tid = threadIdx.x;
    const int r0 = blockIdx.x * GB_ROWS;
    #pragma unroll
    for (int i = 0; i < 8; ++i) {
        int idx = tid + 256 * i;
        int r = idx >> 5, c4 = (idx & 31) * 4;
        int gr = r0 + r;
        float4 v = make_float4(0.f, 0.f, 0.f, 0.f);
        if (gr < nrows) v = *(const float4*)(X + (size_t)gr * 128 + c4);
        *(float4*)(&xt[r][c4]) = v;
    }
    __syncthreads();
    const int c0 = (tid & 31) * 4;
    const int rbase = (tid >> 5) * 8;
    float acc[8][4];
    #pragma unroll
    for (int i = 0; i < 8; ++i)
        #pragma unroll
        for (int j = 0; j < 4; ++j) acc[i][j] = 0.f;
    #pragma unroll 4
    for (int k = 0; k < 128; ++k) {
        float4 w4 = *(const float4*)(W + k * 128 + c0);
        float xv[8];
        #pragma unroll
        for (int i = 0; i < 8; ++i) xv[i] = xt[rbase + i][k];
        #pragma unroll
        for (int i = 0; i < 8; ++i) {
            acc[i][0] = fmaf(xv[i], w4.x, acc[i][0]);
            acc[i][1] = fmaf(xv[i], w4.y, acc[i][1]);
            acc[i][2] = fmaf(xv[i], w4.z, acc[i][2]);
            acc[i][3] = fmaf(xv[i], w4.w, acc[i][3]);
        }
    }
    #pragma unroll
    for (int i = 0; i < 8; ++i) {
        int gr = r0 + rbase + i;
        if (gr < nrows) {
            *(float4*)(Hout + (size_t)gr * 128 + c0) =
                make_float4(acc[i][0], acc[i][1], acc[i][2], acc[i][3]);
            uint2 p;
            p.x = bf16rne(acc[i][0]) | (bf16rne(acc[i][1]) << 16);
            p.y = bf16rne(acc[i][2]) | (bf16rne(acc[i][3]) << 16);
            *(uint2*)(Hb + (size_t)gr * 128 + c0) = p;
        }
    }
}

// ---------------- per-node attention logits ----------------
template <int H>
__global__ __launch_bounds__(256) void alpha_kernel(const float* __restrict__ Hm,
                                                    const float* __restrict__ a_src,
                                                    const float* __restrict__ a_dst,
                                                    float* __restrict__ als,
                                                    float* __restrict__ ald) {
    int wid = ((blockIdx.x * blockDim.x + threadIdx.x) >> 6);
    int lane = threadIdx.x & 63;
    if (wid >= N_NODES) return;
    float v0 = Hm[(size_t)wid * 128 + lane];
    float v1 = Hm[(size_t)wid * 128 + 64 + lane];
    if (H == 2) {
        float s0 = v0 * a_src[lane];
        float s1 = v1 * a_src[64 + lane];
        float d0 = v0 * a_dst[lane];
        float d1 = v1 * a_dst[64 + lane];
        #pragma unroll
        for (int off = 32; off; off >>= 1) {
            s0 += __shfl_down(s0, off);
            s1 += __shfl_down(s1, off);
            d0 += __shfl_down(d0, off);
            d1 += __shfl_down(d1, off);
        }
        if (lane == 0) {
            als[wid * 2] = s0; als[wid * 2 + 1] = s1;
            ald[wid * 2] = d0; ald[wid * 2 + 1] = d1;
        }
    } else {
        float s = v0 * a_src[lane] + v1 * a_src[64 + lane];
        float d = v0 * a_dst[lane] + v1 * a_dst[64 + lane];
        #pragma unroll
        for (int off = 32; off; off >>= 1) {
            s += __shfl_down(s, off);
            d += __shfl_down(d, off);
        }
        if (lane == 0) { als[wid] = s; ald[wid] = d; }
    }
}

// ---- fused softmax+gather v2: lane-parallel softmax, LDS-broadcast gather ----
template <int H, int DO_ELU>
__global__ __launch_bounds__(256) void aggregate_kernel(const unsigned short* __restrict__ Hb,
                                                        const float* __restrict__ als,
                                                        const float* __restrict__ aldv,
                                                        const int* __restrict__ ptr,
                                                        const int* __restrict__ csr,
                                                        const float* __restrict__ bias,
                                                        float* __restrict__ out) {
    __shared__ int   s_src[4][64];
    __shared__ float s_p[4][H][64];
    const int w = threadIdx.x >> 6;
    const int lane = threadIdx.x & 63;
    const int d = blockIdx.x * 4 + w;
    if (d >= N_NODES) return;
    const int head = (H == 2) ? (lane >> 5) : 0;

    int beg = ptr[d], end = ptr[d + 1];

    float ald0, ald1 = 0.f, es0, es1 = 0.f;
    if (H == 2) {
        float2 ta = *(const float2*)(aldv + (size_t)d * 2);
        float2 ts = *(const float2*)(als + (size_t)d * 2);
        ald0 = ta.x; ald1 = ta.y;
        es0 = lrelu(ts.x + ald0); es1 = lrelu(ts.y + ald1);
    } else {
        ald0 = aldv[d]; es0 = lrelu(als[d] + ald0);
    }

    // phase 0: lane-parallel logits + wave max
    int k0 = beg + lane;
    int src0 = 0;
    float e0 = -INFINITY, e1 = -INFINITY;
    if (k0 < end) {
        src0 = csr[k0];
        if (H == 2) {
            float2 t = *(const float2*)(als + (size_t)src0 * 2);
            e0 = lrelu(t.x + ald0); e1 = lrelu(t.y + ald1);
        } else e0 = lrelu(als[src0] + ald0);
    }
    float m0 = fmaxf(es0, e0);
    float m1 = (H == 2) ? fmaxf(es1, e1) : 0.f;
    for (int k = k0 + 64; k < end; k += 64) {   // deg>64: rare recompute path
        int s = csr[k];
        if (H == 2) {
            float2 t = *(const float2*)(als + (size_t)s * 2);
            m0 = fmaxf(m0, lrelu(t.x + ald0));
            m1 = fmaxf(m1, lrelu(t.y + ald1));
        } else m0 = fmaxf(m0, lrelu(als[s] + ald0));
    }
    #pragma unroll
    for (int off = 32; off; off >>= 1) {
        m0 = fmaxf(m0, __shfl_xor(m0, off));
        if (H == 2) m1 = fmaxf(m1, __shfl_xor(m1, off));
    }

    float l0 = 0.f, l1 = 0.f;           // per-lane partial of sum(exp)
    float ax0 = 0.f, ay0 = 0.f, ax1 = 0.f, ay1 = 0.f;  // two acc chains

    for (int t0 = beg; t0 < end; t0 += 64) {
        int cnt = min(64, end - t0);
        // phase A: produce p for this tile (one lane per edge)
        int k = t0 + lane;
        if (k < end) {
            int s; float f0, f1 = 0.f;
            if (t0 == beg) { s = src0; f0 = e0; f1 = e1; }
            else {
                s = csr[k];
                if (H == 2) {
                    float2 t = *(const float2*)(als + (size_t)s * 2);
                    f0 = lrelu(t.x + ald0); f1 = lrelu(t.y + ald1);
                } else f0 = lrelu(als[s] + ald0);
            }
            float p0 = __expf(f0 - m0);
            l0 += p0;
            s_src[w][lane] = s;
            s_p[w][0][lane] = p0;
            if (H == 2) {
                float p1 = __expf(f1 - m1);
                l1 += p1;
                s_p[w][1][lane] = p1;
            }
        }
        // same wave: lockstep + compiler lgkmcnt on LDS dependence
        // phase B: all lanes gather cnt edges (LDS broadcast of p/src)
        int j = 0;
        for (; j + 1 < cnt; j += 2) {
            int sA = s_src[w][j], sB = s_src[w][j + 1];
            float pA = s_p[w][head][j], pB = s_p[w][head][j + 1];
            unsigned uA = ((const unsigned*)(Hb + (size_t)sA * 128))[lane];
            unsigned uB = ((const unsigned*)(Hb + (size_t)sB * 128))[lane];
            ax0 = fmaf(pA, __uint_as_float(uA << 16), ax0);
            ay0 = fmaf(pA, __uint_as_float(uA & 0xffff0000u), ay0);
            ax1 = fmaf(pB, __uint_as_float(uB << 16), ax1);
            ay1 = fmaf(pB, __uint_as_float(uB & 0xffff0000u), ay1);
        }
        if (j < cnt) {
            int sA = s_src[w][j];
            float pA = s_p[w][head][j];
            unsigned uA = ((const unsigned*)(Hb + (size_t)sA * 128))[lane];
            ax0 = fmaf(pA, __uint_as_float(uA << 16), ax0);
            ay0 = fmaf(pA, __uint_as_float(uA & 0xffff0000u), ay0);
        }
    }

    float ax = ax0 + ax1, ay = ay0 + ay1;
    // self-loop contribution
    float mh  = (head == 0) ? m0 : m1;
    float esh = (head == 0) ? es0 : es1;
    float psh = __expf(esh - mh);
    {
        unsigned u = ((const unsigned*)(Hb + (size_t)d * 128))[lane];
        ax = fmaf(psh, __uint_as_float(u << 16), ax);
        ay = fmaf(psh, __uint_as_float(u & 0xffff0000u), ay);
    }
    // reduce sum(exp) across wave
    #pragma unroll
    for (int off = 32; off; off >>= 1) {
        l0 += __shfl_xor(l0, off);
        if (H == 2) l1 += __shfl_xor(l1, off);
    }
    float denom = ((head == 0) ? l0 : l1) + psh;
    float inv = 1.f / (denom + 1e-16f);
    float o0 = ax * inv + bias[2 * lane];
    float o1 = ay * inv + bias[2 * lane + 1];
    if (DO_ELU) {
        o0 = o0 > 0.f ? o0 : expm1f(o0);
        o1 = o1 > 0.f ? o1 : expm1f(o1);
    }
    ((float2*)(out + (size_t)d * 128))[lane] = make_float2(o0, o1);
}

// ---------------- launch ----------------
extern "C" void kernel_launch(void* const* d_in, const int* in_sizes, int n_in,
                              void* d_out, int out_size, void* d_ws, size_t ws_size,
                              hipStream_t stream) {
    const float* x      = (const float*)d_in[0];
    const int*   ei     = (const int*)d_in[1];
    const float* W1     = (const float*)d_in[2];
    const float* a_src1 = (const float*)d_in[3];
    const float* a_dst1 = (const float*)d_in[4];
    const float* b1     = (const float*)d_in[5];
    const float* W2     = (const float*)d_in[6];
    const float* a_src2 = (const float*)d_in[7];
    const float* a_dst2 = (const float*)d_in[8];
    const float* b2     = (const float*)d_in[9];
    float* out = (float*)d_out;

    char* ws = (char*)d_ws;
    size_t off = 0;
    auto alloc = [&](size_t bytes) { void* p = ws + off; off += (bytes + 255) & ~(size_t)255; return p; };
    int*   ptr    = (int*)alloc((N_NODES + 1) * sizeof(int));
    int*   gbcnt  = (int*)alloc(NBUCK * sizeof(int));
    int*   bbase  = (int*)alloc((NBUCK + 1) * sizeof(int));
    int*   bcur   = (int*)alloc(NBUCK * sizeof(int));
    int2*  bpairs = (int2*)alloc((size_t)N_EDGES * sizeof(int2));
    int*   csr    = (int*)alloc(N_EDGES * sizeof(int));
    float* h      = (float*)alloc((size_t)N_NODES * 128 * sizeof(float));
    float* x2     = (float*)alloc((size_t)N_NODES * 128 * sizeof(float));
    unsigned short* hb = (unsigned short*)alloc((size_t)N_NODES * 128 * sizeof(unsigned short));
    float* als    = (float*)alloc(N_NODES * 2 * sizeof(float));
    float* ald    = (float*)alloc(N_NODES * 2 * sizeof(float));

    // ---- CSR build (bucket sort; same graph both layers) ----
    hipMemsetAsync(gbcnt, 0, NBUCK * sizeof(int), stream);
    bucketcount_kernel<<<256, 256, 0, stream>>>(ei, gbcnt);
    bucketscan_kernel<<<1, 256, 0, stream>>>(gbcnt, bbase, bcur);
    bucketscatter_kernel<<<(N_EDGES + CCHUNK - 1) / CCHUNK, 256, 0, stream>>>(ei, bcur, bpairs);
    csrfinalize_kernel<<<NBUCK, 256, 0, stream>>>(bpairs, bbase, ptr, csr);

    int gblocks = (N_NODES + GB_ROWS - 1) / GB_ROWS;
    int wblocks = (N_NODES + 3) / 4;

    // ---- layer 1 ----
    gemm_kernel<<<gblocks, 256, 0, stream>>>(x, W1, h, hb, N_NODES);
    alpha_kernel<2><<<wblocks, 256, 0, stream>>>(h, a_src1, a_dst1, als, ald);
    aggregate_kernel<2, 1><<<wblocks, 256, 0, stream>>>(hb, als, ald, ptr, csr, b1, x2);

    // ---- layer 2 ----
    gemm_kernel<<<gblocks, 256, 0, stream>>>(x2, W2, h, hb, N_NODES);
    alpha_kernel<1><<<wblocks, 256, 0, stream>>>(h, a_src2, a_dst2, als, ald);
    aggregate_kernel<1, 0><<<wblocks, 256, 0, stream>>>(hb, als, ald, ptr, csr, b2, out);
}

// Round 8
// 191.767 us; speedup vs baseline: 1.5489x; 1.1398x over previous
//
#include <hip/hip_runtime.h>
#include <hip/hip_bf16.h>
#include <math.h>

#define N_NODES 50000
#define N_EDGES 800000
#define NEG_SLOPE 0.2f
#define NBUCK ((N_NODES + 255) / 256)   // 196 buckets of 256 dsts
#define CCHUNK 4096
#define DCAP 8192

__device__ inline float lrelu(float x) { return fmaxf(x, NEG_SLOPE * x); }

__device__ inline unsigned bf16rne(float f) {
    unsigned u = __float_as_uint(f);
    return (u + 0x7fffu + ((u >> 16) & 1u)) >> 16;
}

// ---------------- CSR build: LDS-staged bucket sort ----------------
__global__ __launch_bounds__(256) void bucketcount_kernel(const int* __restrict__ ei,
                                                          int* __restrict__ gbcnt) {
    __shared__ int lc[NBUCK];
    for (int i = threadIdx.x; i < NBUCK; i += 256) lc[i] = 0;
    __syncthreads();
    int stride = gridDim.x * 256;
    for (int e = blockIdx.x * 256 + threadIdx.x; e < N_EDGES; e += stride)
        atomicAdd(&lc[ei[N_EDGES + e] >> 8], 1);
    __syncthreads();
    for (int i = threadIdx.x; i < NBUCK; i += 256)
        if (lc[i]) atomicAdd(&gbcnt[i], lc[i]);
}

__global__ __launch_bounds__(256) void bucketscan_kernel(const int* __restrict__ gbcnt,
                                                         int* __restrict__ bbase,
                                                         int* __restrict__ bcur) {
    __shared__ int ss[256];
    int t = threadIdx.x;
    int v = (t < NBUCK) ? gbcnt[t] : 0;
    ss[t] = v;
    __syncthreads();
    for (int d = 1; d < 256; d <<= 1) {
        int u = (t >= d) ? ss[t - d] : 0;
        __syncthreads();
        ss[t] += u;
        __syncthreads();
    }
    int excl = ss[t] - v;
    if (t < NBUCK) { bbase[t] = excl; bcur[t] = excl; }
    if (t == 0) bbase[NBUCK] = N_EDGES;
}

__global__ __launch_bounds__(256) void bucketscatter_kernel(const int* __restrict__ ei,
                                                            int* __restrict__ bcur,
                                                            int2* __restrict__ bpairs) {
    __shared__ int cnt[NBUCK], startl[NBUCK], baseg[NBUCK], cur2[NBUCK];
    __shared__ int ss[256];
    __shared__ int2 stage[CCHUNK];
    int t = threadIdx.x;
    int e0 = blockIdx.x * CCHUNK;
    int nume = min(CCHUNK, N_EDGES - e0);
    for (int i = t; i < NBUCK; i += 256) { cnt[i] = 0; cur2[i] = 0; }
    __syncthreads();
    int src[CCHUNK / 256], dst[CCHUNK / 256];
    #pragma unroll
    for (int j = 0; j < CCHUNK / 256; ++j) {
        int idx = t + j * 256;
        if (idx < nume) {
            src[j] = ei[e0 + idx];
            dst[j] = ei[N_EDGES + e0 + idx];
            atomicAdd(&cnt[dst[j] >> 8], 1);
        } else dst[j] = -1;
    }
    __syncthreads();
    {
        int v = (t < NBUCK) ? cnt[t] : 0;
        ss[t] = v;
        __syncthreads();
        for (int d = 1; d < 256; d <<= 1) {
            int u = (t >= d) ? ss[t - d] : 0;
            __syncthreads();
            ss[t] += u;
            __syncthreads();
        }
        if (t < NBUCK) startl[t] = ss[t] - v;
    }
    __syncthreads();
    if (t < NBUCK && cnt[t] > 0) baseg[t] = atomicAdd(&bcur[t], cnt[t]);
    __syncthreads();
    #pragma unroll
    for (int j = 0; j < CCHUNK / 256; ++j) {
        if (dst[j] >= 0) {
            int b = dst[j] >> 8;
            int slot = startl[b] + atomicAdd(&cur2[b], 1);
            stage[slot] = make_int2(src[j], dst[j]);
        }
    }
    __syncthreads();
    for (int i = t; i < nume; i += 256) {
        int2 p = stage[i];
        int b = p.y >> 8;
        bpairs[baseg[b] + (i - startl[b])] = p;
    }
}

__global__ __launch_bounds__(256) void csrfinalize_kernel(const int2* __restrict__ bpairs,
                                                          const int* __restrict__ bbase,
                                                          int* __restrict__ ptr,
                                                          int* __restrict__ csr) {
    __shared__ int cnt[256], excl[256], cur[256];
    __shared__ int ss[256];
    __shared__ int2 P[DCAP];
    int b = blockIdx.x, t = threadIdx.x;
    int bb = bbase[b], be = bbase[b + 1];
    int n = be - bb;
    int d0 = b << 8;
    int dmax = min(256, N_NODES - d0);
    bool fits = (n <= DCAP);
    cnt[t] = 0; cur[t] = 0;
    __syncthreads();
    for (int i = t; i < n; i += 256) {
        int2 p = bpairs[bb + i];
        if (fits) P[i] = p;
        atomicAdd(&cnt[p.y & 255], 1);
    }
    __syncthreads();
    {
        int v = cnt[t];
        ss[t] = v;
        __syncthreads();
        for (int d = 1; d < 256; d <<= 1) {
            int u = (t >= d) ? ss[t - d] : 0;
            __syncthreads();
            ss[t] += u;
            __syncthreads();
        }
        excl[t] = ss[t] - v;
    }
    __syncthreads();
    if (t < dmax) ptr[d0 + t] = bb + excl[t];
    if (b == NBUCK - 1 && t == 0) ptr[N_NODES] = N_EDGES;
    for (int i = t; i < n; i += 256) {
        int2 p = fits ? P[i] : bpairs[bb + i];
        int ld = p.y & 255;
        int pos = bb + excl[ld] + atomicAdd(&cur[ld], 1);
        csr[pos] = p.x;
    }
}

// ---- GEMM + fused attention-logit epilogue ----
// H[n][c] = sum_k X[n][k]*W[k][c]; writes bf16 Hb and als/ald (dot with a_src/a_dst).
#define GB_ROWS 64
template <int H>
__global__ __launch_bounds__(256) void gemm_kernel(const float* __restrict__ X,
                                                   const float* __restrict__ W,
                                                   const float* __restrict__ asrc,
                                                   const float* __restrict__ adst,
                                                   unsigned short* __restrict__ Hb,
                                                   float* __restrict__ als,
                                                   float* __restrict__ ald,
                                                   int nrows) {
    __shared__ float xt[GB_ROWS][132];
    const int tid = threadIdx.x;
    const int r0 = blockIdx.x * GB_ROWS;
    #pragma unroll
    for (int i = 0; i < 8; ++i) {
        int idx = tid + 256 * i;
        int r = idx >> 5, c4 = (idx & 31) * 4;
        int gr = r0 + r;
        float4 v = make_float4(0.f, 0.f, 0.f, 0.f);
        if (gr < nrows) v = *(const float4*)(X + (size_t)gr * 128 + c4);
        *(float4*)(&xt[r][c4]) = v;
    }
    __syncthreads();
    const int c0 = (tid & 31) * 4;
    const int rbase = (tid >> 5) * 8;
    const int q = tid & 31;
    float acc[8][4];
    #pragma unroll
    for (int i = 0; i < 8; ++i)
        #pragma unroll
        for (int j = 0; j < 4; ++j) acc[i][j] = 0.f;
    #pragma unroll 4
    for (int k = 0; k < 128; ++k) {
        float4 w4 = *(const float4*)(W + k * 128 + c0);
        float xv[8];
        #pragma unroll
        for (int i = 0; i < 8; ++i) xv[i] = xt[rbase + i][k];
        #pragma unroll
        for (int i = 0; i < 8; ++i) {
            acc[i][0] = fmaf(xv[i], w4.x, acc[i][0]);
            acc[i][1] = fmaf(xv[i], w4.y, acc[i][1]);
            acc[i][2] = fmaf(xv[i], w4.z, acc[i][2]);
            acc[i][3] = fmaf(xv[i], w4.w, acc[i][3]);
        }
    }
    float4 as4 = *(const float4*)(asrc + c0);
    float4 ad4 = *(const float4*)(adst + c0);
    #pragma unroll
    for (int i = 0; i < 8; ++i) {
        int gr = r0 + rbase + i;
        bool ok = gr < nrows;
        if (ok) {
            uint2 p;
            p.x = bf16rne(acc[i][0]) | (bf16rne(acc[i][1]) << 16);
            p.y = bf16rne(acc[i][2]) | (bf16rne(acc[i][3]) << 16);
            *(uint2*)(Hb + (size_t)gr * 128 + c0) = p;
        }
        float sp = acc[i][0] * as4.x + acc[i][1] * as4.y + acc[i][2] * as4.z + acc[i][3] * as4.w;
        float dp = acc[i][0] * ad4.x + acc[i][1] * ad4.y + acc[i][2] * ad4.z + acc[i][3] * ad4.w;
        #pragma unroll
        for (int off = 1; off < (H == 2 ? 16 : 32); off <<= 1) {
            sp += __shfl_xor(sp, off);
            dp += __shfl_xor(dp, off);
        }
        if (ok) {
            if (H == 2) {
                if (q == 0)  { als[(size_t)gr * 2]     = sp; ald[(size_t)gr * 2]     = dp; }
                if (q == 16) { als[(size_t)gr * 2 + 1] = sp; ald[(size_t)gr * 2 + 1] = dp; }
            } else {
                if (q == 0) { als[gr] = sp; ald[gr] = dp; }
            }
        }
    }
}

// ---- fused softmax+gather: lane-parallel softmax, LDS-broadcast gather ----
template <int H, int DO_ELU>
__global__ __launch_bounds__(256) void aggregate_kernel(const unsigned short* __restrict__ Hb,
                                                        const float* __restrict__ als,
                                                        const float* __restrict__ aldv,
                                                        const int* __restrict__ ptr,
                                                        const int* __restrict__ csr,
                                                        const float* __restrict__ bias,
                                                        float* __restrict__ out) {
    __shared__ int   s_src[4][64];
    __shared__ float s_p[4][H][64];
    const int w = threadIdx.x >> 6;
    const int lane = threadIdx.x & 63;
    const int d = blockIdx.x * 4 + w;
    if (d >= N_NODES) return;
    const int head = (H == 2) ? (lane >> 5) : 0;

    int beg = ptr[d], end = ptr[d + 1];

    float ald0, ald1 = 0.f, es0, es1 = 0.f;
    if (H == 2) {
        float2 ta = *(const float2*)(aldv + (size_t)d * 2);
        float2 ts = *(const float2*)(als + (size_t)d * 2);
        ald0 = ta.x; ald1 = ta.y;
        es0 = lrelu(ts.x + ald0); es1 = lrelu(ts.y + ald1);
    } else {
        ald0 = aldv[d]; es0 = lrelu(als[d] + ald0);
    }

    // phase 0: lane-parallel logits + wave max
    int k0 = beg + lane;
    int src0 = 0;
    float e0 = -INFINITY, e1 = -INFINITY;
    if (k0 < end) {
        src0 = csr[k0];
        if (H == 2) {
            float2 t = *(const float2*)(als + (size_t)src0 * 2);
            e0 = lrelu(t.x + ald0); e1 = lrelu(t.y + ald1);
        } else e0 = lrelu(als[src0] + ald0);
    }
    float m0 = fmaxf(es0, e0);
    float m1 = (H == 2) ? fmaxf(es1, e1) : 0.f;
    for (int k = k0 + 64; k < end; k += 64) {   // deg>64: rare recompute path
        int s = csr[k];
        if (H == 2) {
            float2 t = *(const float2*)(als + (size_t)s * 2);
            m0 = fmaxf(m0, lrelu(t.x + ald0));
            m1 = fmaxf(m1, lrelu(t.y + ald1));
        } else m0 = fmaxf(m0, lrelu(als[s] + ald0));
    }
    #pragma unroll
    for (int off = 32; off; off >>= 1) {
        m0 = fmaxf(m0, __shfl_xor(m0, off));
        if (H == 2) m1 = fmaxf(m1, __shfl_xor(m1, off));
    }

    float l0 = 0.f, l1 = 0.f;
    float ax0 = 0.f, ay0 = 0.f, ax1 = 0.f, ay1 = 0.f;
    float ax2 = 0.f, ay2 = 0.f, ax3 = 0.f, ay3 = 0.f;

    for (int t0 = beg; t0 < end; t0 += 64) {
        int cnt = min(64, end - t0);
        // phase A: produce p for this tile (one lane per edge)
        int k = t0 + lane;
        if (k < end) {
            int s; float f0, f1 = 0.f;
            if (t0 == beg) { s = src0; f0 = e0; f1 = e1; }
            else {
                s = csr[k];
                if (H == 2) {
                    float2 t = *(const float2*)(als + (size_t)s * 2);
                    f0 = lrelu(t.x + ald0); f1 = lrelu(t.y + ald1);
                } else f0 = lrelu(als[s] + ald0);
            }
            float p0 = __expf(f0 - m0);
            l0 += p0;
            s_src[w][lane] = s;
            s_p[w][0][lane] = p0;
            if (H == 2) {
                float p1 = __expf(f1 - m1);
                l1 += p1;
                s_p[w][1][lane] = p1;
            }
        }
        // phase B: all lanes gather cnt edges; 4 independent load/acc chains
        int j = 0;
        for (; j + 3 < cnt; j += 4) {
            int sA = s_src[w][j],     sB = s_src[w][j + 1];
            int sC = s_src[w][j + 2], sD = s_src[w][j + 3];
            float pA = s_p[w][head][j],     pB = s_p[w][head][j + 1];
            float pC = s_p[w][head][j + 2], pD = s_p[w][head][j + 3];
            unsigned uA = ((const unsigned*)(Hb + (size_t)sA * 128))[lane];
            unsigned uB = ((const unsigned*)(Hb + (size_t)sB * 128))[lane];
            unsigned uC = ((const unsigned*)(Hb + (size_t)sC * 128))[lane];
            unsigned uD = ((const unsigned*)(Hb + (size_t)sD * 128))[lane];
            ax0 = fmaf(pA, __uint_as_float(uA << 16), ax0);
            ay0 = fmaf(pA, __uint_as_float(uA & 0xffff0000u), ay0);
            ax1 = fmaf(pB, __uint_as_float(uB << 16), ax1);
            ay1 = fmaf(pB, __uint_as_float(uB & 0xffff0000u), ay1);
            ax2 = fmaf(pC, __uint_as_float(uC << 16), ax2);
            ay2 = fmaf(pC, __uint_as_float(uC & 0xffff0000u), ay2);
            ax3 = fmaf(pD, __uint_as_float(uD << 16), ax3);
            ay3 = fmaf(pD, __uint_as_float(uD & 0xffff0000u), ay3);
        }
        for (; j < cnt; ++j) {
            int sA = s_src[w][j];
            float pA = s_p[w][head][j];
            unsigned uA = ((const unsigned*)(Hb + (size_t)sA * 128))[lane];
            ax0 = fmaf(pA, __uint_as_float(uA << 16), ax0);
            ay0 = fmaf(pA, __uint_as_float(uA & 0xffff0000u), ay0);
        }
    }

    float ax = (ax0 + ax1) + (ax2 + ax3);
    float ay = (ay0 + ay1) + (ay2 + ay3);
    // self-loop contribution
    float mh  = (head == 0) ? m0 : m1;
    float esh = (head == 0) ? es0 : es1;
    float psh = __expf(esh - mh);
    {
        unsigned u = ((const unsigned*)(Hb + (size_t)d * 128))[lane];
        ax = fmaf(psh, __uint_as_float(u << 16), ax);
        ay = fmaf(psh, __uint_as_float(u & 0xffff0000u), ay);
    }
    #pragma unroll
    for (int off = 32; off; off >>= 1) {
        l0 += __shfl_xor(l0, off);
        if (H == 2) l1 += __shfl_xor(l1, off);
    }
    float denom = ((head == 0) ? l0 : l1) + psh;
    float inv = 1.f / (denom + 1e-16f);
    float o0 = ax * inv + bias[2 * lane];
    float o1 = ay * inv + bias[2 * lane + 1];
    if (DO_ELU) {
        o0 = o0 > 0.f ? o0 : expm1f(o0);
        o1 = o1 > 0.f ? o1 : expm1f(o1);
    }
    ((float2*)(out + (size_t)d * 128))[lane] = make_float2(o0, o1);
}

// ---------------- launch ----------------
extern "C" void kernel_launch(void* const* d_in, const int* in_sizes, int n_in,
                              void* d_out, int out_size, void* d_ws, size_t ws_size,
                              hipStream_t stream) {
    const float* x      = (const float*)d_in[0];
    const int*   ei     = (const int*)d_in[1];
    const float* W1     = (const float*)d_in[2];
    const float* a_src1 = (const float*)d_in[3];
    const float* a_dst1 = (const float*)d_in[4];
    const float* b1     = (const float*)d_in[5];
    const float* W2     = (const float*)d_in[6];
    const float* a_src2 = (const float*)d_in[7];
    const float* a_dst2 = (const float*)d_in[8];
    const float* b2     = (const float*)d_in[9];
    float* out = (float*)d_out;

    char* ws = (char*)d_ws;
    size_t off = 0;
    auto alloc = [&](size_t bytes) { void* p = ws + off; off += (bytes + 255) & ~(size_t)255; return p; };
    int*   ptr    = (int*)alloc((N_NODES + 1) * sizeof(int));
    int*   gbcnt  = (int*)alloc(NBUCK * sizeof(int));
    int*   bbase  = (int*)alloc((NBUCK + 1) * sizeof(int));
    int*   bcur   = (int*)alloc(NBUCK * sizeof(int));
    int2*  bpairs = (int2*)alloc((size_t)N_EDGES * sizeof(int2));
    int*   csr    = (int*)alloc(N_EDGES * sizeof(int));
    float* x2     = (float*)alloc((size_t)N_NODES * 128 * sizeof(float));
    unsigned short* hb = (unsigned short*)alloc((size_t)N_NODES * 128 * sizeof(unsigned short));
    float* als    = (float*)alloc(N_NODES * 2 * sizeof(float));
    float* ald    = (float*)alloc(N_NODES * 2 * sizeof(float));

    // ---- CSR build (bucket sort; same graph both layers) ----
    hipMemsetAsync(gbcnt, 0, NBUCK * sizeof(int), stream);
    bucketcount_kernel<<<256, 256, 0, stream>>>(ei, gbcnt);
    bucketscan_kernel<<<1, 256, 0, stream>>>(gbcnt, bbase, bcur);
    bucketscatter_kernel<<<(N_EDGES + CCHUNK - 1) / CCHUNK, 256, 0, stream>>>(ei, bcur, bpairs);
    csrfinalize_kernel<<<NBUCK, 256, 0, stream>>>(bpairs, bbase, ptr, csr);

    int gblocks = (N_NODES + GB_ROWS - 1) / GB_ROWS;
    int wblocks = (N_NODES + 3) / 4;

    // ---- layer 1 ----
    gemm_kernel<2><<<gblocks, 256, 0, stream>>>(x, W1, a_src1, a_dst1, hb, als, ald, N_NODES);
    aggregate_kernel<2, 1><<<wblocks, 256, 0, stream>>>(hb, als, ald, ptr, csr, b1, x2);

    // ---- layer 2 ----
    gemm_kernel<1><<<gblocks, 256, 0, stream>>>(x2, W2, a_src2, a_dst2, hb, als, ald, N_NODES);
    aggregate_kernel<1, 0><<<wblocks, 256, 0, stream>>>(hb, als, ald, ptr, csr, b2, out);
}